// Round 1
// baseline (6844.504 us; speedup 1.0000x reference)
//
#include <hip/hip_runtime.h>
#include <hip/hip_bf16.h>
#include <math.h>

#define D_MODEL 1024
#define T_SEQ   2048
#define NB      2
#define NH      16
#define HDIM    64
#define BT      (NB * T_SEQ)   // 4096 rows total

// ---------------- block-wide 2-value sum reduction (256 threads, 4 waves) ----
__device__ __forceinline__ void block_reduce_2(float& s, float& s2) {
#pragma unroll
  for (int off = 32; off > 0; off >>= 1) {
    s  += __shfl_xor(s,  off);
    s2 += __shfl_xor(s2, off);
  }
  __shared__ float sm[8];
  int lane = threadIdx.x & 63;
  int w    = threadIdx.x >> 6;
  if (lane == 0) { sm[w * 2] = s; sm[w * 2 + 1] = s2; }
  __syncthreads();
  s  = sm[0] + sm[2] + sm[4] + sm[6];
  s2 = sm[1] + sm[3] + sm[5] + sm[7];
}

// ---------------- embed + pos + LN1 (one block per row) ---------------------
__global__ __launch_bounds__(256) void k_embed_ln1(
    const int* __restrict__ x, const float* __restrict__ emb,
    const float* __restrict__ pos, const float* __restrict__ g,
    const float* __restrict__ bta, float* __restrict__ h, float* __restrict__ h1)
{
  int r    = blockIdx.x;
  int tpos = r & (T_SEQ - 1);
  int idx  = x[r];
  int d    = threadIdx.x * 4;

  float4 e = *(const float4*)&emb[(size_t)idx * D_MODEL + d];
  float4 p = *(const float4*)&pos[(size_t)tpos * D_MODEL + d];
  float4 v = make_float4(e.x + p.x, e.y + p.y, e.z + p.z, e.w + p.w);
  *(float4*)&h[(size_t)r * D_MODEL + d] = v;

  float s  = v.x + v.y + v.z + v.w;
  float s2 = v.x * v.x + v.y * v.y + v.z * v.z + v.w * v.w;
  block_reduce_2(s, s2);
  float mu   = s  * (1.0f / D_MODEL);
  float var  = s2 * (1.0f / D_MODEL) - mu * mu;
  float rstd = rsqrtf(var + 1e-5f);

  float4 gv = *(const float4*)&g[d];
  float4 bv = *(const float4*)&bta[d];
  float4 o;
  o.x = (v.x - mu) * rstd * gv.x + bv.x;
  o.y = (v.y - mu) * rstd * gv.y + bv.y;
  o.z = (v.z - mu) * rstd * gv.z + bv.z;
  o.w = (v.w - mu) * rstd * gv.w + bv.w;
  *(float4*)&h1[(size_t)r * D_MODEL + d] = o;
}

// ---------------- plain LN (one block per row) ------------------------------
__global__ __launch_bounds__(256) void k_ln(
    const float* __restrict__ in, const float* __restrict__ g,
    const float* __restrict__ bta, float* __restrict__ outp)
{
  int r = blockIdx.x;
  int d = threadIdx.x * 4;
  float4 v = *(const float4*)&in[(size_t)r * D_MODEL + d];
  float s  = v.x + v.y + v.z + v.w;
  float s2 = v.x * v.x + v.y * v.y + v.z * v.z + v.w * v.w;
  block_reduce_2(s, s2);
  float mu   = s  * (1.0f / D_MODEL);
  float var  = s2 * (1.0f / D_MODEL) - mu * mu;
  float rstd = rsqrtf(var + 1e-5f);
  float4 gv = *(const float4*)&g[d];
  float4 bv = *(const float4*)&bta[d];
  float4 o;
  o.x = (v.x - mu) * rstd * gv.x + bv.x;
  o.y = (v.y - mu) * rstd * gv.y + bv.y;
  o.z = (v.z - mu) * rstd * gv.z + bv.z;
  o.w = (v.w - mu) * rstd * gv.w + bv.w;
  *(float4*)&outp[(size_t)r * D_MODEL + d] = o;
}

// ---------------- fp32 tiled GEMM: C = A(MxK) @ B(KxN) [+bias][gelu][+res] --
// 128x128 tile, TK=8, 256 threads, 8x8 per thread (2x2 blocks of 4x4).
__global__ __launch_bounds__(256) void k_gemm(
    const float* __restrict__ A, const float* __restrict__ B,
    const float* __restrict__ bias, const float* __restrict__ res,
    float* __restrict__ C, int M, int N, int K, int act)
{
  __shared__ float As[8][132];
  __shared__ float Bs[8][132];
  int t  = threadIdx.x;
  int tx = t & 15, ty = t >> 4;
  int bm = blockIdx.y * 128, bn = blockIdx.x * 128;

  int arow = t >> 1;          // 0..127
  int akc  = (t & 1) * 4;     // 0 or 4
  int bkr  = t >> 5;          // 0..7
  int bcol = (t & 31) * 4;    // 0..124

  const float* Aptr = A + (size_t)(bm + arow) * K + akc;
  const float* Bptr = B + (size_t)bkr * N + bn + bcol;

  float acc[2][2][4][4];
#pragma unroll
  for (int p = 0; p < 2; p++)
#pragma unroll
    for (int q = 0; q < 2; q++)
#pragma unroll
      for (int i = 0; i < 4; i++)
#pragma unroll
        for (int j = 0; j < 4; j++) acc[p][q][i][j] = 0.0f;

  for (int k0 = 0; k0 < K; k0 += 8) {
    float4 av = *(const float4*)(Aptr + k0);
    float4 bv = *(const float4*)(Bptr + (size_t)k0 * N);
    __syncthreads();
    As[akc + 0][arow] = av.x;
    As[akc + 1][arow] = av.y;
    As[akc + 2][arow] = av.z;
    As[akc + 3][arow] = av.w;
    *(float4*)&Bs[bkr][bcol] = bv;
    __syncthreads();
#pragma unroll
    for (int kk = 0; kk < 8; kk++) {
      float a[2][4], b[2][4];
      *(float4*)a[0] = *(const float4*)&As[kk][ty * 4];
      *(float4*)a[1] = *(const float4*)&As[kk][64 + ty * 4];
      *(float4*)b[0] = *(const float4*)&Bs[kk][tx * 4];
      *(float4*)b[1] = *(const float4*)&Bs[kk][64 + tx * 4];
#pragma unroll
      for (int p = 0; p < 2; p++)
#pragma unroll
        for (int i = 0; i < 4; i++)
#pragma unroll
          for (int q = 0; q < 2; q++)
#pragma unroll
            for (int j = 0; j < 4; j++)
              acc[p][q][i][j] = fmaf(a[p][i], b[q][j], acc[p][q][i][j]);
    }
  }

#pragma unroll
  for (int p = 0; p < 2; p++)
#pragma unroll
    for (int i = 0; i < 4; i++) {
      int row = bm + p * 64 + ty * 4 + i;
#pragma unroll
      for (int q = 0; q < 2; q++) {
        int col = bn + q * 64 + tx * 4;
        float4 v = make_float4(acc[p][q][i][0], acc[p][q][i][1],
                               acc[p][q][i][2], acc[p][q][i][3]);
        if (bias) {
          float4 bb = *(const float4*)&bias[col];
          v.x += bb.x; v.y += bb.y; v.z += bb.z; v.w += bb.w;
        }
        if (act == 1) {  // exact GELU
          v.x = 0.5f * v.x * (1.0f + erff(v.x * 0.70710678118654752f));
          v.y = 0.5f * v.y * (1.0f + erff(v.y * 0.70710678118654752f));
          v.z = 0.5f * v.z * (1.0f + erff(v.z * 0.70710678118654752f));
          v.w = 0.5f * v.w * (1.0f + erff(v.w * 0.70710678118654752f));
        }
        if (res) {
          float4 rv = *(const float4*)&res[(size_t)row * N + col];
          v.x += rv.x; v.y += rv.y; v.z += rv.z; v.w += rv.w;
        }
        *(float4*)&C[(size_t)row * N + col] = v;
      }
    }
}

// ---------------- flash attention: one block per (b, head, 64-row q-tile) ---
__global__ __launch_bounds__(256) void k_attn(
    const float* __restrict__ qkv, float* __restrict__ outp)
{
  int qi = blockIdx.x;   // q-tile 0..31
  int hh = blockIdx.y;   // head 0..15
  int b  = blockIdx.z;   // batch 0..1

  __shared__ float Qs[64][68];
  __shared__ float Kts[64][68];  // transposed: [d][k]
  __shared__ float Vs[64][68];   // [k][d]
  __shared__ float Ps[64][68];   // [r][k]

  int t  = threadIdx.x;
  int tx = t & 15, ty = t >> 4;
  int q0 = qi * 64;
  const size_t rs = 3 * 1024;  // qkv row stride
  const float* base = qkv + (size_t)b * T_SEQ * rs + hh * HDIM;

#pragma unroll
  for (int rep = 0; rep < 4; rep++) {
    int idx = rep * 256 + t;
    int r   = idx >> 4;
    int d0  = (idx & 15) * 4;
    float4 qv = *(const float4*)(base + (size_t)(q0 + r) * rs + d0);
    *(float4*)&Qs[r][d0] = qv;
  }

  float m_run[4], l_run[4], o[4][4];
#pragma unroll
  for (int i = 0; i < 4; i++) {
    m_run[i] = -1e30f; l_run[i] = 0.0f;
#pragma unroll
    for (int j = 0; j < 4; j++) o[i][j] = 0.0f;
  }

  for (int kt = 0; kt <= qi; kt++) {
    int k0 = kt * 64;
    __syncthreads();  // previous PV / staging reads done
#pragma unroll
    for (int rep = 0; rep < 4; rep++) {
      int idx = rep * 256 + t;
      int r   = idx >> 4;
      int d0  = (idx & 15) * 4;
      float4 kv = *(const float4*)(base + 1024 + (size_t)(k0 + r) * rs + d0);
      Kts[d0 + 0][r] = kv.x; Kts[d0 + 1][r] = kv.y;
      Kts[d0 + 2][r] = kv.z; Kts[d0 + 3][r] = kv.w;
      float4 vv = *(const float4*)(base + 2048 + (size_t)(k0 + r) * rs + d0);
      *(float4*)&Vs[r][d0] = vv;
    }
    __syncthreads();

    // S = Q K^T for this tile
    float s[4][4] = {{0.f,0.f,0.f,0.f},{0.f,0.f,0.f,0.f},
                     {0.f,0.f,0.f,0.f},{0.f,0.f,0.f,0.f}};
#pragma unroll
    for (int d0 = 0; d0 < 64; d0 += 4) {
      float qv[4][4], kv[4][4];
#pragma unroll
      for (int i = 0; i < 4; i++)
        *(float4*)qv[i] = *(const float4*)&Qs[ty * 4 + i][d0];
#pragma unroll
      for (int dd = 0; dd < 4; dd++)
        *(float4*)kv[dd] = *(const float4*)&Kts[d0 + dd][tx * 4];
#pragma unroll
      for (int dd = 0; dd < 4; dd++)
#pragma unroll
        for (int i = 0; i < 4; i++)
#pragma unroll
          for (int j = 0; j < 4; j++)
            s[i][j] = fmaf(qv[i][dd], kv[dd][j], s[i][j]);
    }

    const float scale = 0.125f;  // 1/sqrt(64)
    if (kt == qi) {
#pragma unroll
      for (int i = 0; i < 4; i++)
#pragma unroll
        for (int j = 0; j < 4; j++)
          s[i][j] = (tx * 4 + j <= ty * 4 + i) ? s[i][j] * scale : -1e30f;
    } else {
#pragma unroll
      for (int i = 0; i < 4; i++)
#pragma unroll
        for (int j = 0; j < 4; j++) s[i][j] *= scale;
    }

    // online softmax (row groups = 16 lanes sharing ty)
#pragma unroll
    for (int i = 0; i < 4; i++) {
      float mx = fmaxf(fmaxf(s[i][0], s[i][1]), fmaxf(s[i][2], s[i][3]));
#pragma unroll
      for (int off = 1; off < 16; off <<= 1) mx = fmaxf(mx, __shfl_xor(mx, off));
      float mn    = fmaxf(m_run[i], mx);
      float alpha = __expf(m_run[i] - mn);
      float p[4], rsum = 0.0f;
#pragma unroll
      for (int j = 0; j < 4; j++) { p[j] = __expf(s[i][j] - mn); rsum += p[j]; }
#pragma unroll
      for (int off = 1; off < 16; off <<= 1) rsum += __shfl_xor(rsum, off);
      l_run[i] = l_run[i] * alpha + rsum;
      m_run[i] = mn;
#pragma unroll
      for (int j = 0; j < 4; j++) o[i][j] *= alpha;
      *(float4*)&Ps[ty * 4 + i][tx * 4] = make_float4(p[0], p[1], p[2], p[3]);
    }
    __syncthreads();

    // O += P V   (thread owns rows ty*4+i, dims tx*4+j)
#pragma unroll 8
    for (int k = 0; k < 64; k++) {
      float pv[4];
#pragma unroll
      for (int i = 0; i < 4; i++) pv[i] = Ps[ty * 4 + i][k];
      float4 vv = *(const float4*)&Vs[k][tx * 4];
#pragma unroll
      for (int i = 0; i < 4; i++) {
        o[i][0] = fmaf(pv[i], vv.x, o[i][0]);
        o[i][1] = fmaf(pv[i], vv.y, o[i][1]);
        o[i][2] = fmaf(pv[i], vv.z, o[i][2]);
        o[i][3] = fmaf(pv[i], vv.w, o[i][3]);
      }
    }
  }

  float* obase = outp + (size_t)(b * T_SEQ + q0) * D_MODEL + hh * HDIM;
#pragma unroll
  for (int i = 0; i < 4; i++) {
    float inv = 1.0f / l_run[i];
    float4 ov = make_float4(o[i][0] * inv, o[i][1] * inv,
                            o[i][2] * inv, o[i][3] * inv);
    *(float4*)&obase[(size_t)(ty * 4 + i) * D_MODEL + tx * 4] = ov;
  }
}

// ---------------- launcher --------------------------------------------------
extern "C" void kernel_launch(void* const* d_in, const int* in_sizes, int n_in,
                              void* d_out, int out_size, void* d_ws, size_t ws_size,
                              hipStream_t stream)
{
  const int*   x      = (const int*)d_in[0];
  const float* emb    = (const float*)d_in[1];
  const float* pos    = (const float*)d_in[2];
  const float* w_qkv  = (const float*)d_in[3];
  const float* w_out  = (const float*)d_in[4];
  const float* ln1_g  = (const float*)d_in[5];
  const float* ln1_b  = (const float*)d_in[6];
  const float* ln2_g  = (const float*)d_in[7];
  const float* ln2_b  = (const float*)d_in[8];
  const float* w_ffn1 = (const float*)d_in[9];
  const float* b_ffn1 = (const float*)d_in[10];
  const float* w_ffn2 = (const float*)d_in[11];
  const float* b_ffn2 = (const float*)d_in[12];
  const float* w_head = (const float*)d_in[13];
  const float* b_head = (const float*)d_in[14];
  float* outp = (float*)d_out;

  float* ws   = (float*)d_ws;
  float* h    = ws;                                  // 4096x1024
  float* h1   = h    + (size_t)BT * D_MODEL;         // 4096x1024
  float* qkv  = h1   + (size_t)BT * D_MODEL;         // 4096x3072
  float* attn = qkv  + (size_t)BT * 3 * D_MODEL;     // 4096x1024
  float* h2   = attn + (size_t)BT * D_MODEL;         // 4096x1024
  float* mid  = h2   + (size_t)BT * D_MODEL;         // 4096x4096

  k_embed_ln1<<<BT, 256, 0, stream>>>(x, emb, pos, ln1_g, ln1_b, h, h1);

  // qkv = h1 @ w_qkv                      (4096x1024 @ 1024x3072)
  k_gemm<<<dim3(3072 / 128, BT / 128), 256, 0, stream>>>(
      h1, w_qkv, nullptr, nullptr, qkv, BT, 3072, 1024, 0);

  // causal flash attention -> attn (B,T,INNER)
  k_attn<<<dim3(T_SEQ / 64, NH, NB), 256, 0, stream>>>(qkv, attn);

  // h = h + attn @ w_out                  (4096x1024 @ 1024x1024, res=h)
  k_gemm<<<dim3(1024 / 128, BT / 128), 256, 0, stream>>>(
      attn, w_out, nullptr, h, h, BT, 1024, 1024, 0);

  // h2 = LN2(h)
  k_ln<<<BT, 256, 0, stream>>>(h, ln2_g, ln2_b, h2);

  // mid = gelu(h2 @ w_ffn1 + b_ffn1)      (4096x1024 @ 1024x4096)
  k_gemm<<<dim3(4096 / 128, BT / 128), 256, 0, stream>>>(
      h2, w_ffn1, b_ffn1, nullptr, mid, BT, 4096, 1024, 1);

  // h = h + mid @ w_ffn2 + b_ffn2         (4096x4096 @ 4096x1024, res=h)
  k_gemm<<<dim3(1024 / 128, BT / 128), 256, 0, stream>>>(
      mid, w_ffn2, b_ffn2, h, h, BT, 1024, 4096, 0);

  // logits = h @ w_head + b_head          (4096x1024 @ 1024x32000)
  k_gemm<<<dim3(32000 / 128, BT / 128), 256, 0, stream>>>(
      h, w_head, b_head, nullptr, outp, BT, 32000, 1024, 0);
}